// Round 2
// baseline (386.742 us; speedup 1.0000x reference)
//
#include <hip/hip_runtime.h>
#include <math.h>

#define AR_P 48
#define FLEN 168
#define HISTLEN 336
#define TCHUNK 24

// ws layout (fp32): [0, 8064) W[t][k] de-standardized-dot coeffs, [8064, 8232) cc[t]

// One wave. Companion-matrix power recurrence:
//   r_0 = phi;  r_{t+1}[k] = r_t[k-1] + r_t[47]*phi[k]   (r_t[-1] == 0)
//   pred_t(std) = bias*(1 + sum_{m<t} r_m[47]) + r_t . s0
//   mu_orig[b,t] = cc[t] + sum_k W[t,k]*(y[b,k]-mu),  W=r, cc folds bias/sigma/mu
__global__ void k_coeffs(const float* __restrict__ phi,
                         const float* __restrict__ bias,
                         const float* __restrict__ mu_p,
                         const float* __restrict__ sigma_p,
                         float* __restrict__ ws) {
    const int k = threadIdx.x;  // 64 threads, 1 wave
    float* W  = ws;
    float* cc = ws + AR_P * FLEN;
    const float mu     = mu_p[0];
    const float sigma  = sigma_p[0];
    const float bias_f = bias[0];
    const float phik = (k < AR_P) ? phi[k] : 0.0f;

    float r = phik;     // r_0 = phi
    float csum = 0.0f;  // sum_{m<t} r_m[47]
    for (int t = 0; t < FLEN; ++t) {
        if (k < AR_P) W[t * AR_P + k] = r;
        if (k == 0)   cc[t] = bias_f * (1.0f + csum) * sigma + mu;
        float r47 = __shfl(r, AR_P - 1, 64);
        csum += r47;
        float up = __shfl_up(r, 1, 64);
        float rn = (k == 0 ? 0.0f : up) + r47 * phik;
        r = (k < AR_P) ? rn : 0.0f;
    }
}

// One thread per (batch row, 24-wide t-chunk). blockIdx.y in [0,7) selects chunk.
__global__ __launch_bounds__(256) void k_mu(
    const float* __restrict__ enc_l,
    const float* __restrict__ ws,
    const float* __restrict__ mu_p,
    float* __restrict__ out,  // [B*168] mu part
    int B) {
    const float* W  = ws;
    const float* cc = ws + AR_P * FLEN;
    const int b  = blockIdx.x * blockDim.x + threadIdx.x;
    const int t0 = blockIdx.y * TCHUNK;
    if (b >= B) return;
    const float mu = mu_p[0];

    // last 48 fp32 history values: 192 B at byte offset 1344*b + 1152 (16B aligned)
    float ym[AR_P];
    const float4* yp = reinterpret_cast<const float4*>(
        enc_l + (size_t)b * HISTLEN + (HISTLEN - AR_P));
#pragma unroll
    for (int i = 0; i < AR_P / 4; ++i) {
        float4 q = yp[i];
        ym[i * 4 + 0] = q.x - mu;
        ym[i * 4 + 1] = q.y - mu;
        ym[i * 4 + 2] = q.z - mu;
        ym[i * 4 + 3] = q.w - mu;
    }

    float acc[TCHUNK];
#pragma unroll
    for (int j = 0; j < TCHUNK; ++j) acc[j] = cc[t0 + j];
    // W/cc indices are wave-uniform (blockIdx + unrolled constants) -> s_load,
    // FMA takes the SGPR as one operand; 24 independent accumulators for ILP.
#pragma unroll
    for (int k = 0; k < AR_P; ++k) {
        const float y = ym[k];
#pragma unroll
        for (int j = 0; j < TCHUNK; ++j)
            acc[j] = fmaf(W[(t0 + j) * AR_P + k], y, acc[j]);
    }

    // 24 floats = 6 x float4, byte offset 672*b + 96*chunk (16B aligned)
    float4* dst = reinterpret_cast<float4*>(out + (size_t)b * FLEN + t0);
    const float4* av = reinterpret_cast<const float4*>(acc);
#pragma unroll
    for (int i = 0; i < TCHUNK / 4; ++i) dst[i] = av[i];
}

// Constant logvar fill: fully coalesced grid-stride float4.
__global__ __launch_bounds__(256) void k_fill(
    float* __restrict__ out,               // points at logvar half
    const float* __restrict__ log_sigma2,
    const float* __restrict__ sigma_p,
    size_t n4) {
    const float lv = log_sigma2[0] + 2.0f * logf(sigma_p[0]);
    const float4 v = make_float4(lv, lv, lv, lv);
    float4* o = reinterpret_cast<float4*>(out);
    size_t i = (size_t)blockIdx.x * blockDim.x + threadIdx.x;
    const size_t stride = (size_t)gridDim.x * blockDim.x;
    for (; i < n4; i += stride) o[i] = v;
}

extern "C" void kernel_launch(void* const* d_in, const int* in_sizes, int n_in,
                              void* d_out, int out_size, void* d_ws, size_t ws_size,
                              hipStream_t stream) {
    const float* enc_l = (const float*)d_in[0];
    // d_in[1..3] = enc_t, enc_w, enc_s (unused by the reference)
    const float* phi  = (const float*)d_in[4];
    const float* bias = (const float*)d_in[5];
    const float* ls2  = (const float*)d_in[6];
    const float* mu   = (const float*)d_in[7];
    const float* sg   = (const float*)d_in[8];
    float* ws  = (float*)d_ws;
    float* out = (float*)d_out;
    const int B = in_sizes[0] / HISTLEN;

    hipLaunchKernelGGL(k_coeffs, dim3(1), dim3(64), 0, stream,
                       phi, bias, mu, sg, ws);
    hipLaunchKernelGGL(k_mu, dim3((B + 255) / 256, FLEN / TCHUNK), dim3(256), 0, stream,
                       enc_l, ws, mu, out, B);
    const size_t n4 = (size_t)B * FLEN / 4;
    hipLaunchKernelGGL(k_fill, dim3(4096), dim3(256), 0, stream,
                       out + (size_t)B * FLEN, ls2, sg, n4);
}